// Round 1
// baseline (294.665 us; speedup 1.0000x reference)
//
#include <hip/hip_runtime.h>
#include <hip/hip_bf16.h>
#include <stdint.h>

#define BB 8
#define CC 512
#define SS 1024
#define NH 8
#define DK 64
#define MM (BB*SS)      // 8192 rows
#define HD (NH*DK)      // 512
#define LP 88           // LDS pitch in bf16 elems: 176B rows -> 16B-aligned, 2-way banks

typedef __attribute__((ext_vector_type(8))) short bf16x8;
typedef __attribute__((ext_vector_type(4))) float f32x4;

__device__ inline float b2f(unsigned short u) {
    union { unsigned int i; float f; } x; x.i = ((unsigned int)u) << 16; return x.f;
}
__device__ inline unsigned short f2b(float f) {
    union { float f; unsigned int i; } x; x.f = f;
    unsigned int r = (x.i + 0x7FFFu + ((x.i >> 16) & 1u)) >> 16;
    return (unsigned short)r;
}
__device__ inline f32x4 mfma16(bf16x8 a, bf16x8 b, f32x4 c) {
    return __builtin_amdgcn_mfma_f32_16x16x32_bf16(a, b, c, 0, 0, 0);
}

// ---------------- weight transpose + bf16 cast: w[K][N] -> wT[N][K] ----------------
__global__ void wtrans_kernel(const float* __restrict__ wq, const float* __restrict__ wk,
                              const float* __restrict__ wv, const float* __restrict__ wo,
                              unsigned short* __restrict__ wT) {
    __shared__ float lds[32][33];
    const float* w = (blockIdx.z == 0) ? wq : (blockIdx.z == 1) ? wk : (blockIdx.z == 2) ? wv : wo;
    unsigned short* o = wT + (size_t)blockIdx.z * (512 * 512);
    const int n0 = blockIdx.x * 32, k0 = blockIdx.y * 32;
    const int tx = threadIdx.x, ty = threadIdx.y;   // 32 x 8
#pragma unroll
    for (int i = 0; i < 4; ++i)
        lds[ty + 8 * i][tx] = w[(size_t)(k0 + ty + 8 * i) * 512 + n0 + tx];
    __syncthreads();
#pragma unroll
    for (int i = 0; i < 4; ++i)
        o[(size_t)(n0 + ty + 8 * i) * 512 + k0 + tx] = f2b(lds[tx][ty + 8 * i]);
}

// ---------------- LayerNorm over C, [B,C,S] -> tn bf16 [B*S][C] ----------------
__global__ void __launch_bounds__(256) ln_kernel(const float* __restrict__ x,
                                                 const float* __restrict__ g,
                                                 const float* __restrict__ bta,
                                                 unsigned short* __restrict__ tn) {
    const int t = threadIdx.x, lane = t & 63, w = t >> 6;
    const int gs = blockIdx.x * 4 + w;            // 0..8191
    const int b = gs >> 10, s = gs & 1023;
    const float* xb = x + (size_t)b * 512 * 1024 + s;
    float v[8], sum = 0.f, sq = 0.f;
#pragma unroll
    for (int i = 0; i < 8; ++i) {
        int c = i * 64 + lane;
        float tv = xb[(size_t)c * 1024];
        v[i] = tv; sum += tv; sq += tv * tv;
    }
#pragma unroll
    for (int m = 1; m <= 32; m <<= 1) { sum += __shfl_xor(sum, m); sq += __shfl_xor(sq, m); }
    const float mean = sum * (1.f / 512.f);
    const float var = sq * (1.f / 512.f) - mean * mean;
    const float rstd = rsqrtf(var + 1e-5f);
#pragma unroll
    for (int i = 0; i < 8; ++i) {
        int c = i * 64 + lane;
        float o = (v[i] - mean) * rstd * g[c] + bta[c];
        tn[(size_t)gs * 512 + c] = f2b(o);
    }
}

// ---------------- shared 128x128 GEMM core (reg-staged LDS, padded) ----------------
// A [M][512] bf16 row-major, Bt [N][512] bf16 (i.e. B transposed, n-major)
__device__ inline void gemm_tile(const unsigned short* __restrict__ A,
                                 const unsigned short* __restrict__ Bt,
                                 int m0, int n0,
                                 unsigned short* A_lds, unsigned short* B_lds,
                                 f32x4 acc[4][4]) {
    const int t = threadIdx.x;
    const int lane = t & 63, w = t >> 6;
    const int l15 = lane & 15, l4 = lane >> 4;
    const int wm = (w >> 1) * 64, wn = (w & 1) * 64;
#pragma unroll 1
    for (int kt = 0; kt < 8; ++kt) {
        uint4 ra[4], rb[4];
#pragma unroll
        for (int i = 0; i < 4; ++i) {
            int chunk = i * 256 + t;
            int row = chunk >> 3, kc = (chunk & 7) * 8;
            ra[i] = *(const uint4*)(A + (size_t)(m0 + row) * 512 + kt * 64 + kc);
            rb[i] = *(const uint4*)(Bt + (size_t)(n0 + row) * 512 + kt * 64 + kc);
        }
        __syncthreads();   // prior iteration's LDS reads complete
#pragma unroll
        for (int i = 0; i < 4; ++i) {
            int chunk = i * 256 + t;
            int row = chunk >> 3, kc = (chunk & 7) * 8;
            *(uint4*)&A_lds[row * LP + kc] = ra[i];
            *(uint4*)&B_lds[row * LP + kc] = rb[i];
        }
        __syncthreads();
#pragma unroll
        for (int kk = 0; kk < 2; ++kk) {
            bf16x8 af[4], bfr[4];
#pragma unroll
            for (int i = 0; i < 4; ++i)
                af[i] = *(const bf16x8*)&A_lds[(wm + i * 16 + l15) * LP + kk * 32 + l4 * 8];
#pragma unroll
            for (int j = 0; j < 4; ++j)
                bfr[j] = *(const bf16x8*)&B_lds[(wn + j * 16 + l15) * LP + kk * 32 + l4 * 8];
#pragma unroll
            for (int i = 0; i < 4; ++i)
#pragma unroll
                for (int j = 0; j < 4; ++j)
                    acc[i][j] = mfma16(af[i], bfr[j], acc[i][j]);
        }
    }
}

// ---------------- QKV projection GEMM ----------------
__global__ void __launch_bounds__(256) gemm_qkv_kernel(const unsigned short* __restrict__ tn,
                                                       const unsigned short* __restrict__ wT,
                                                       const float* __restrict__ bq,
                                                       const float* __restrict__ bk,
                                                       const float* __restrict__ bv,
                                                       unsigned short* __restrict__ qkv) {
    __shared__ alignas(16) unsigned short A_lds[128 * LP];
    __shared__ alignas(16) unsigned short B_lds[128 * LP];
    const int z = blockIdx.z;
    const unsigned short* Bt = wT + (size_t)z * (512 * 512);
    const float* bias = (z == 0) ? bq : (z == 1) ? bk : bv;
    unsigned short* out = qkv + (size_t)z * MM * 512;
    const int m0 = blockIdx.x * 128, n0 = blockIdx.y * 128;
    f32x4 acc[4][4];
    const f32x4 z4 = {0.f, 0.f, 0.f, 0.f};
#pragma unroll
    for (int i = 0; i < 4; ++i)
#pragma unroll
        for (int j = 0; j < 4; ++j) acc[i][j] = z4;
    gemm_tile(tn, Bt, m0, n0, A_lds, B_lds, acc);
    const int lane = threadIdx.x & 63, w = threadIdx.x >> 6;
    const int l15 = lane & 15, l4 = lane >> 4;
    const int wm = (w >> 1) * 64, wn = (w & 1) * 64;
#pragma unroll
    for (int i = 0; i < 4; ++i)
#pragma unroll
        for (int j = 0; j < 4; ++j)
#pragma unroll
            for (int r = 0; r < 4; ++r) {
                int row = m0 + wm + i * 16 + l4 * 4 + r;
                int col = n0 + wn + j * 16 + l15;
                out[(size_t)row * 512 + col] = f2b(acc[i][j][r] + bias[col]);
            }
}

// ---------------- flash attention: S=1024, D=64, per-(b,h,qtile) ----------------
__global__ void __launch_bounds__(256) attn_kernel(const unsigned short* __restrict__ q,
                                                   const unsigned short* __restrict__ k,
                                                   const unsigned short* __restrict__ v,
                                                   unsigned short* __restrict__ o) {
    __shared__ alignas(16) unsigned short K_lds[64 * LP];    // [key][d]
    __shared__ alignas(16) unsigned short VT_lds[64 * LP];   // [d][key]
    __shared__ alignas(16) unsigned short P_lds[4][16 * LP]; // per-wave [q][key]
    const int qt = blockIdx.x, h = blockIdx.y, b = blockIdx.z;
    const int t = threadIdx.x, lane = t & 63, w = t >> 6;
    const int l15 = lane & 15, l4 = lane >> 4;

    // Q fragments for this wave's 16 rows, pre-scaled by 1/sqrt(64)=0.125 (exact in bf16)
    const int qrow = qt * 64 + w * 16 + l15;
    const unsigned short* qp = q + ((size_t)(b * SS + qrow) * NH + h) * DK;
    bf16x8 qf[2];
#pragma unroll
    for (int kk = 0; kk < 2; ++kk) {
        bf16x8 tmp = *(const bf16x8*)(qp + kk * 32 + l4 * 8);
#pragma unroll
        for (int e = 0; e < 8; ++e)
            tmp[e] = (short)f2b(b2f((unsigned short)tmp[e]) * 0.125f);
        qf[kk] = tmp;
    }

    float m_run[4], l_run[4];
    f32x4 acc_o[4];
    const f32x4 z4 = {0.f, 0.f, 0.f, 0.f};
#pragma unroll
    for (int r = 0; r < 4; ++r) { m_run[r] = -1e30f; l_run[r] = 0.f; }
#pragma unroll
    for (int j = 0; j < 4; ++j) acc_o[j] = z4;

    const int vkey = t >> 2, vd0 = (t & 3) * 16;

#pragma unroll 1
    for (int kt = 0; kt < 16; ++kt) {
        const int key0 = kt * 64;
        // K tile: 2 x 16B chunks per thread
        uint4 rk[2]; int krow[2], kkc[2];
#pragma unroll
        for (int i = 0; i < 2; ++i) {
            int chunk = i * 256 + t;
            krow[i] = chunk >> 3; kkc[i] = (chunk & 7) * 8;
            rk[i] = *(const uint4*)(k + ((size_t)(b * SS + key0 + krow[i]) * NH + h) * DK + kkc[i]);
        }
        // V tile: this thread owns (key=vkey, d=vd0..vd0+15)
        uint4 rv[2];
#pragma unroll
        for (int i = 0; i < 2; ++i)
            rv[i] = *(const uint4*)(v + ((size_t)(b * SS + key0 + vkey) * NH + h) * DK + vd0 + i * 8);
        __syncthreads();   // all waves finished reading prior K/V tiles
#pragma unroll
        for (int i = 0; i < 2; ++i)
            *(uint4*)&K_lds[krow[i] * LP + kkc[i]] = rk[i];
#pragma unroll
        for (int i = 0; i < 2; ++i) {
            const unsigned short* pv = (const unsigned short*)&rv[i];
#pragma unroll
            for (int e = 0; e < 8; ++e)
                VT_lds[(vd0 + i * 8 + e) * LP + vkey] = pv[e];
        }
        __syncthreads();

        // scores = (Q/8) @ K^T  -> per-wave 16q x 64key
        f32x4 sc[4];
#pragma unroll
        for (int j = 0; j < 4; ++j) sc[j] = z4;
#pragma unroll
        for (int kk = 0; kk < 2; ++kk)
#pragma unroll
            for (int j = 0; j < 4; ++j) {
                bf16x8 kf = *(const bf16x8*)&K_lds[(j * 16 + l15) * LP + kk * 32 + l4 * 8];
                sc[j] = mfma16(qf[kk], kf, sc[j]);
            }

        // online softmax; lane holds rows (l4*4+r), col l15 within each 16-key group j
#pragma unroll
        for (int r = 0; r < 4; ++r) {
            float mx = fmaxf(fmaxf(sc[0][r], sc[1][r]), fmaxf(sc[2][r], sc[3][r]));
            mx = fmaxf(mx, __shfl_xor(mx, 1));
            mx = fmaxf(mx, __shfl_xor(mx, 2));
            mx = fmaxf(mx, __shfl_xor(mx, 4));
            mx = fmaxf(mx, __shfl_xor(mx, 8));
            float mnew = fmaxf(m_run[r], mx);
            float scl = __expf(m_run[r] - mnew);
            float ps = 0.f;
#pragma unroll
            for (int j = 0; j < 4; ++j) {
                float p = __expf(sc[j][r] - mnew);
                ps += p;
                P_lds[w][(l4 * 4 + r) * LP + j * 16 + l15] = f2b(p);
            }
            ps += __shfl_xor(ps, 1);
            ps += __shfl_xor(ps, 2);
            ps += __shfl_xor(ps, 4);
            ps += __shfl_xor(ps, 8);
            l_run[r] = l_run[r] * scl + ps;
            m_run[r] = mnew;
#pragma unroll
            for (int j = 0; j < 4; ++j) acc_o[j][r] *= scl;
        }

        // O += P @ V  (P from wave-private LDS; V^T gives key-contiguous B frags)
#pragma unroll
        for (int kk = 0; kk < 2; ++kk) {
            bf16x8 pf = *(const bf16x8*)&P_lds[w][l15 * LP + kk * 32 + l4 * 8];
#pragma unroll
            for (int j = 0; j < 4; ++j) {
                bf16x8 vf = *(const bf16x8*)&VT_lds[(j * 16 + l15) * LP + kk * 32 + l4 * 8];
                acc_o[j] = mfma16(pf, vf, acc_o[j]);
            }
        }
    }

#pragma unroll
    for (int j = 0; j < 4; ++j)
#pragma unroll
        for (int r = 0; r < 4; ++r) {
            int row = qt * 64 + w * 16 + l4 * 4 + r;
            float val = acc_o[j][r] / l_run[r];
            o[((size_t)(b * SS + row) * NH + h) * DK + j * 16 + l15] = f2b(val);
        }
}

// ---------------- output projection + bias + residual ----------------
__global__ void __launch_bounds__(256) gemm_out_kernel(const unsigned short* __restrict__ ao,
                                                       const unsigned short* __restrict__ woT,
                                                       const float* __restrict__ bo,
                                                       const float* __restrict__ x,
                                                       float* __restrict__ out) {
    __shared__ alignas(16) unsigned short A_lds[128 * LP];
    __shared__ alignas(16) unsigned short B_lds[128 * LP];
    const int m0 = blockIdx.x * 128, n0 = blockIdx.y * 128;
    f32x4 acc[4][4];
    const f32x4 z4 = {0.f, 0.f, 0.f, 0.f};
#pragma unroll
    for (int i = 0; i < 4; ++i)
#pragma unroll
        for (int j = 0; j < 4; ++j) acc[i][j] = z4;
    gemm_tile(ao, woT, m0, n0, A_lds, B_lds, acc);
    const int lane = threadIdx.x & 63, w = threadIdx.x >> 6;
    const int l15 = lane & 15, l4 = lane >> 4;
    const int wm = (w >> 1) * 64, wn = (w & 1) * 64;
#pragma unroll
    for (int i = 0; i < 4; ++i)
#pragma unroll
        for (int j = 0; j < 4; ++j)
#pragma unroll
            for (int r = 0; r < 4; ++r) {
                int row = m0 + wm + i * 16 + l4 * 4 + r;
                int col = n0 + wn + j * 16 + l15;
                int bi = row >> 10, srow = row & 1023;
                float resid = x[((size_t)bi * 512 + col) * 1024 + srow];
                out[(size_t)row * 512 + col] = acc[i][j][r] + bo[col] + resid;
            }
}

extern "C" void kernel_launch(void* const* d_in, const int* in_sizes, int n_in,
                              void* d_out, int out_size, void* d_ws, size_t ws_size,
                              hipStream_t stream) {
    const float* x   = (const float*)d_in[0];
    const float* wq  = (const float*)d_in[1];
    const float* bq  = (const float*)d_in[2];
    const float* wk  = (const float*)d_in[3];
    const float* bk  = (const float*)d_in[4];
    const float* wv  = (const float*)d_in[5];
    const float* bv  = (const float*)d_in[6];
    const float* lng = (const float*)d_in[7];
    const float* lnb = (const float*)d_in[8];
    const float* wo  = (const float*)d_in[9];
    const float* bo  = (const float*)d_in[10];
    float* out = (float*)d_out;

    unsigned short* ws  = (unsigned short*)d_ws;
    unsigned short* tn  = ws;                                // 4M elems (8 MB)
    unsigned short* qkv = ws + (size_t)4 * 1024 * 1024;      // 12M elems (24 MB): q|k|v
    unsigned short* wT  = ws + (size_t)16 * 1024 * 1024;     // 1M elems (2 MB): wqT|wkT|wvT|woT
    unsigned short* ao  = tn;                                // reuse tn region for attention out

    wtrans_kernel<<<dim3(16, 16, 4), dim3(32, 8), 0, stream>>>(wq, wk, wv, wo, wT);
    ln_kernel<<<2048, 256, 0, stream>>>(x, lng, lnb, tn);
    gemm_qkv_kernel<<<dim3(64, 4, 3), 256, 0, stream>>>(tn, wT, bq, bk, bv, qkv);
    attn_kernel<<<dim3(16, 8, 8), 256, 0, stream>>>(qkv,
                                                    qkv + (size_t)MM * 512,
                                                    qkv + (size_t)2 * MM * 512,
                                                    ao);
    gemm_out_kernel<<<dim3(64, 4), 256, 0, stream>>>(ao, wT + (size_t)3 * 512 * 512, bo, x, out);
}

// Round 2
// 205.427 us; speedup vs baseline: 1.4344x; 1.4344x over previous
//
#include <hip/hip_runtime.h>
#include <hip/hip_bf16.h>
#include <stdint.h>

#define BB 8
#define CC 512
#define SS 1024
#define NH 8
#define DK 64
#define MM (BB*SS)      // 8192 rows
#define PP 104          // P_lds pitch (elems): 208B rows, 16B-aligned

typedef __attribute__((ext_vector_type(8))) short bf16x8;
typedef __attribute__((ext_vector_type(4))) float f32x4;

__device__ inline float b2f(unsigned short u) {
    union { unsigned int i; float f; } x; x.i = ((unsigned int)u) << 16; return x.f;
}
__device__ inline unsigned short f2b(float f) {
    union { float f; unsigned int i; } x; x.f = f;
    unsigned int r = (x.i + 0x7FFFu + ((x.i >> 16) & 1u)) >> 16;
    return (unsigned short)r;
}
__device__ inline f32x4 mfma16(bf16x8 a, bf16x8 b, f32x4 c) {
    return __builtin_amdgcn_mfma_f32_16x16x32_bf16(a, b, c, 0, 0, 0);
}
__device__ __forceinline__ void gload16(const void* g, void* l) {
    __builtin_amdgcn_global_load_lds(
        (const __attribute__((address_space(1))) void*)g,
        (__attribute__((address_space(3))) void*)l, 16, 0, 0);
}

// ---------------- weight transpose + bf16 cast: w[K][N] -> wT[N][K] ----------------
__global__ void wtrans_kernel(const float* __restrict__ wq, const float* __restrict__ wk,
                              const float* __restrict__ wv, const float* __restrict__ wo,
                              unsigned short* __restrict__ wT) {
    __shared__ float lds[32][33];
    const float* w = (blockIdx.z == 0) ? wq : (blockIdx.z == 1) ? wk : (blockIdx.z == 2) ? wv : wo;
    unsigned short* o = wT + (size_t)blockIdx.z * (512 * 512);
    const int n0 = blockIdx.x * 32, k0 = blockIdx.y * 32;
    const int tx = threadIdx.x, ty = threadIdx.y;   // 32 x 8
#pragma unroll
    for (int i = 0; i < 4; ++i)
        lds[ty + 8 * i][tx] = w[(size_t)(k0 + ty + 8 * i) * 512 + n0 + tx];
    __syncthreads();
#pragma unroll
    for (int i = 0; i < 4; ++i)
        o[(size_t)(n0 + ty + 8 * i) * 512 + k0 + tx] = f2b(lds[tx][ty + 8 * i]);
}

// ---------------- x transpose: x fp32 [B][C][S] -> xt bf16 [B][S][C] ----------------
__global__ void xtrans_kernel(const float* __restrict__ x, unsigned short* __restrict__ xt) {
    __shared__ float lds[32][33];
    const int s0 = blockIdx.x * 32, c0 = blockIdx.y * 32, b = blockIdx.z;
    const int tx = threadIdx.x, ty = threadIdx.y;   // 32 x 8
#pragma unroll
    for (int i = 0; i < 4; ++i)
        lds[ty + 8 * i][tx] = x[((size_t)b * 512 + c0 + ty + 8 * i) * 1024 + s0 + tx];
    __syncthreads();
#pragma unroll
    for (int i = 0; i < 4; ++i)
        xt[((size_t)b * 1024 + s0 + ty + 8 * i) * 512 + c0 + tx] = f2b(lds[tx][ty + 8 * i]);
}

// ---------------- LayerNorm over C on xt rows -> tn bf16 [B*S][C] ----------------
__global__ void __launch_bounds__(256) ln_kernel(const unsigned short* __restrict__ xt,
                                                 const float* __restrict__ g,
                                                 const float* __restrict__ bta,
                                                 unsigned short* __restrict__ tn) {
    const int t = threadIdx.x, lane = t & 63, w = t >> 6;
    const int row = blockIdx.x * 4 + w;           // 0..8191
    bf16x8 v = *(const bf16x8*)(xt + (size_t)row * 512 + lane * 8);
    float f[8], sum = 0.f, sq = 0.f;
#pragma unroll
    for (int e = 0; e < 8; ++e) { f[e] = b2f((unsigned short)v[e]); sum += f[e]; sq += f[e] * f[e]; }
#pragma unroll
    for (int m = 1; m <= 32; m <<= 1) { sum += __shfl_xor(sum, m); sq += __shfl_xor(sq, m); }
    const float mean = sum * (1.f / 512.f);
    const float var = sq * (1.f / 512.f) - mean * mean;
    const float rstd = rsqrtf(var + 1e-5f);
    const float4 g0 = *(const float4*)(g + lane * 8), g1 = *(const float4*)(g + lane * 8 + 4);
    const float4 b0 = *(const float4*)(bta + lane * 8), b1 = *(const float4*)(bta + lane * 8 + 4);
    const float gg[8] = {g0.x, g0.y, g0.z, g0.w, g1.x, g1.y, g1.z, g1.w};
    const float bb[8] = {b0.x, b0.y, b0.z, b0.w, b1.x, b1.y, b1.z, b1.w};
    bf16x8 out;
#pragma unroll
    for (int e = 0; e < 8; ++e)
        out[e] = (short)f2b((f[e] - mean) * rstd * gg[e] + bb[e]);
    *(bf16x8*)(tn + (size_t)row * 512 + lane * 8) = out;
}

// ---------------- shared m97-style 128x128 GEMM core (global_load_lds, linear LDS) ----
// A [M][512] bf16 row-major, Bt [N][512] bf16 (B transposed, n-major)
__device__ inline void gemm_tile(const unsigned short* __restrict__ A,
                                 const unsigned short* __restrict__ Bt,
                                 int m0, int n0,
                                 unsigned short* A_lds, unsigned short* B_lds,
                                 f32x4 acc[4][4]) {
    const int t = threadIdx.x;
    const int lane = t & 63, w = t >> 6;
    const int l15 = lane & 15, l4 = lane >> 4;
    const int wm = (w >> 1) * 64, wn = (w & 1) * 64;
#pragma unroll 1
    for (int kt = 0; kt < 8; ++kt) {
        __syncthreads();   // all waves done reading previous tile
#pragma unroll
        for (int i = 0; i < 4; ++i) {
            int chunk = i * 256 + t;
            int row = chunk >> 3, kc = (chunk & 7) * 8;
            gload16(A + (size_t)(m0 + row) * 512 + kt * 64 + kc, &A_lds[chunk * 8]);
            gload16(Bt + (size_t)(n0 + row) * 512 + kt * 64 + kc, &B_lds[chunk * 8]);
        }
        __syncthreads();   // + implicit vmcnt(0): tile resident
#pragma unroll
        for (int kk = 0; kk < 2; ++kk) {
            bf16x8 af[4], bfr[4];
#pragma unroll
            for (int i = 0; i < 4; ++i)
                af[i] = *(const bf16x8*)&A_lds[(wm + i * 16 + l15) * 64 + kk * 32 + l4 * 8];
#pragma unroll
            for (int j = 0; j < 4; ++j)
                bfr[j] = *(const bf16x8*)&B_lds[(wn + j * 16 + l15) * 64 + kk * 32 + l4 * 8];
#pragma unroll
            for (int i = 0; i < 4; ++i)
#pragma unroll
                for (int j = 0; j < 4; ++j)
                    acc[i][j] = mfma16(af[i], bfr[j], acc[i][j]);
        }
    }
}

// ---------------- QKV projection GEMM; V written pre-transposed [b][h][d][s] --------
__global__ void __launch_bounds__(256) gemm_qkv_kernel(const unsigned short* __restrict__ tn,
                                                       const unsigned short* __restrict__ wT,
                                                       const float* __restrict__ bq,
                                                       const float* __restrict__ bk,
                                                       const float* __restrict__ bv,
                                                       unsigned short* __restrict__ outbase) {
    __shared__ alignas(16) unsigned short A_lds[128 * 64];
    __shared__ alignas(16) unsigned short B_lds[128 * 64];
    const int z = blockIdx.z;
    const unsigned short* Bt = wT + (size_t)z * (512 * 512);
    const float* bias = (z == 0) ? bq : (z == 1) ? bk : bv;
    const int m0 = blockIdx.x * 128, n0 = blockIdx.y * 128;
    f32x4 acc[4][4];
    const f32x4 z4 = {0.f, 0.f, 0.f, 0.f};
#pragma unroll
    for (int i = 0; i < 4; ++i)
#pragma unroll
        for (int j = 0; j < 4; ++j) acc[i][j] = z4;
    gemm_tile(tn, Bt, m0, n0, A_lds, B_lds, acc);
    const int lane = threadIdx.x & 63, w = threadIdx.x >> 6;
    const int l15 = lane & 15, l4 = lane >> 4;
    const int wm = (w >> 1) * 64, wn = (w & 1) * 64;
    if (z < 2) {
        unsigned short* out = outbase + (size_t)z * MM * 512;
#pragma unroll
        for (int i = 0; i < 4; ++i)
#pragma unroll
            for (int j = 0; j < 4; ++j) {
                int col = n0 + wn + j * 16 + l15;
                float bcol = bias[col];
#pragma unroll
                for (int r = 0; r < 4; ++r) {
                    int row = m0 + wm + i * 16 + l4 * 4 + r;
                    out[(size_t)row * 512 + col] = f2b(acc[i][j][r] + bcol);
                }
            }
    } else {
        // vt[(b*512 + col)*1024 + s], 4 consecutive s per lane -> 8B packed store
        unsigned short* vt = outbase + (size_t)2 * MM * 512;
#pragma unroll
        for (int i = 0; i < 4; ++i)
#pragma unroll
            for (int j = 0; j < 4; ++j) {
                int col = n0 + wn + j * 16 + l15;
                float bcol = bias[col];
                int rowb = m0 + wm + i * 16 + l4 * 4;
                int bi = rowb >> 10, s0 = rowb & 1023;
                unsigned int lo = (unsigned int)f2b(acc[i][j][0] + bcol) |
                                  ((unsigned int)f2b(acc[i][j][1] + bcol) << 16);
                unsigned int hi = (unsigned int)f2b(acc[i][j][2] + bcol) |
                                  ((unsigned int)f2b(acc[i][j][3] + bcol) << 16);
                uint2 pk; pk.x = lo; pk.y = hi;
                *(uint2*)&vt[((size_t)bi * 512 + col) * 1024 + s0] = pk;
            }
    }
}

// ---------------- flash attention v2: async staging, swizzled LDS, no V transpose ----
__global__ void __launch_bounds__(256) attn_kernel(const unsigned short* __restrict__ q,
                                                   const unsigned short* __restrict__ k,
                                                   const unsigned short* __restrict__ vt,
                                                   unsigned short* __restrict__ o) {
    __shared__ alignas(16) unsigned short Kl[2][64 * 64];   // [key][d], source-swizzled
    __shared__ alignas(16) unsigned short Vl[2][64 * 64];   // [d][key], source-swizzled
    __shared__ alignas(16) unsigned short Pl[4][16 * PP];   // per-wave [q][key]
    const int qt = blockIdx.x, h = blockIdx.y, b = blockIdx.z;
    const int t = threadIdx.x, lane = t & 63, w = t >> 6;
    const int l15 = lane & 15, l4 = lane >> 4;

    // Q fragments, pre-scaled by 1/sqrt(64)
    const int qrow = qt * 64 + w * 16 + l15;
    const unsigned short* qp = q + ((size_t)(b * SS + qrow)) * 512 + h * 64;
    bf16x8 qf[2];
#pragma unroll
    for (int kk = 0; kk < 2; ++kk) {
        bf16x8 tmp = *(const bf16x8*)(qp + kk * 32 + l4 * 8);
#pragma unroll
        for (int e = 0; e < 8; ++e)
            tmp[e] = (short)f2b(b2f((unsigned short)tmp[e]) * 0.125f);
        qf[kk] = tmp;
    }

    const unsigned short* krow_base = k + ((size_t)(b * SS)) * 512 + h * 64;
    const unsigned short* vrow_base = vt + ((size_t)(b * NH + h) * DK) * SS;

    // staging: linear LDS dest, XOR-swizzled global source (involution on byte bits 4-6)
    auto STAGE = [&](int bi, int kt) {
        const int key0 = kt * 64;
#pragma unroll
        for (int i = 0; i < 2; ++i) {
            int chunk = i * 256 + t;
            int row = chunk >> 3;
            int scb = ((chunk & 7) * 16) ^ ((row & 7) << 4);
            gload16((const char*)(krow_base + (size_t)(key0 + row) * 512) + scb,
                    &Kl[bi][chunk * 8]);
            gload16((const char*)(vrow_base + (size_t)row * SS + key0) + scb,
                    &Vl[bi][chunk * 8]);
        }
    };

    float m_run[4], l_run[4];
    f32x4 acc_o[4];
    const f32x4 z4 = {0.f, 0.f, 0.f, 0.f};
#pragma unroll
    for (int r = 0; r < 4; ++r) { m_run[r] = -1e30f; l_run[r] = 0.f; }
#pragma unroll
    for (int j = 0; j < 4; ++j) acc_o[j] = z4;

    STAGE(0, 0);
    __syncthreads();

#pragma unroll 1
    for (int kt = 0; kt < 16; ++kt) {
        const int bi = kt & 1;
        if (kt < 15) STAGE(bi ^ 1, kt + 1);   // issue next tile early; drained at barrier

        // scores = (Q/8) @ K^T -> per-wave 16q x 64key
        f32x4 sc[4];
#pragma unroll
        for (int j = 0; j < 4; ++j) sc[j] = z4;
#pragma unroll
        for (int kk = 0; kk < 2; ++kk)
#pragma unroll
            for (int j = 0; j < 4; ++j) {
                int row = j * 16 + l15;
                int cb = (kk * 64 + l4 * 16) ^ ((row & 7) << 4);
                bf16x8 kf = *(const bf16x8*)((const char*)Kl[bi] + row * 128 + cb);
                sc[j] = mfma16(qf[kk], kf, sc[j]);
            }

        // online softmax; lane holds rows q=l4*4+r, col l15 within each 16-key group j
#pragma unroll
        for (int r = 0; r < 4; ++r) {
            float mx = fmaxf(fmaxf(sc[0][r], sc[1][r]), fmaxf(sc[2][r], sc[3][r]));
            mx = fmaxf(mx, __shfl_xor(mx, 1));
            mx = fmaxf(mx, __shfl_xor(mx, 2));
            mx = fmaxf(mx, __shfl_xor(mx, 4));
            mx = fmaxf(mx, __shfl_xor(mx, 8));
            float mnew = fmaxf(m_run[r], mx);
            float scl = __expf(m_run[r] - mnew);
            float ps = 0.f;
#pragma unroll
            for (int j = 0; j < 4; ++j) {
                float p = __expf(sc[j][r] - mnew);
                ps += p;
                Pl[w][(l4 * 4 + r) * PP + j * 16 + l15] = f2b(p);
            }
            ps += __shfl_xor(ps, 1);
            ps += __shfl_xor(ps, 2);
            ps += __shfl_xor(ps, 4);
            ps += __shfl_xor(ps, 8);
            l_run[r] = l_run[r] * scl + ps;
            m_run[r] = mnew;
#pragma unroll
            for (int j = 0; j < 4; ++j) acc_o[j][r] *= scl;
        }

        // O += P @ V  (V^T staged: key-contiguous B fragments)
#pragma unroll
        for (int kk = 0; kk < 2; ++kk) {
            bf16x8 pf = *(const bf16x8*)&Pl[w][l15 * PP + kk * 32 + l4 * 8];
#pragma unroll
            for (int j = 0; j < 4; ++j) {
                int row = j * 16 + l15;
                int cb = (kk * 64 + l4 * 16) ^ ((row & 7) << 4);
                bf16x8 vf = *(const bf16x8*)((const char*)Vl[bi] + row * 128 + cb);
                acc_o[j] = mfma16(pf, vf, acc_o[j]);
            }
        }

        __syncthreads();   // implicit vmcnt(0): next tile resident; reads of buf done
    }

#pragma unroll
    for (int j = 0; j < 4; ++j)
#pragma unroll
        for (int r = 0; r < 4; ++r) {
            int row = qt * 64 + w * 16 + l4 * 4 + r;
            float val = acc_o[j][r] / l_run[r];
            o[((size_t)(b * SS + row)) * 512 + h * 64 + j * 16 + l15] = f2b(val);
        }
}

// ---------------- output projection + bias + residual (coalesced bf16 resid) --------
__global__ void __launch_bounds__(256) gemm_out_kernel(const unsigned short* __restrict__ ao,
                                                       const unsigned short* __restrict__ woT,
                                                       const float* __restrict__ bo,
                                                       const unsigned short* __restrict__ xt,
                                                       float* __restrict__ out) {
    __shared__ alignas(16) unsigned short A_lds[128 * 64];
    __shared__ alignas(16) unsigned short B_lds[128 * 64];
    const int m0 = blockIdx.x * 128, n0 = blockIdx.y * 128;
    f32x4 acc[4][4];
    const f32x4 z4 = {0.f, 0.f, 0.f, 0.f};
#pragma unroll
    for (int i = 0; i < 4; ++i)
#pragma unroll
        for (int j = 0; j < 4; ++j) acc[i][j] = z4;
    gemm_tile(ao, woT, m0, n0, A_lds, B_lds, acc);
    const int lane = threadIdx.x & 63, w = threadIdx.x >> 6;
    const int l15 = lane & 15, l4 = lane >> 4;
    const int wm = (w >> 1) * 64, wn = (w & 1) * 64;
#pragma unroll
    for (int i = 0; i < 4; ++i)
#pragma unroll
        for (int j = 0; j < 4; ++j) {
            int col = n0 + wn + j * 16 + l15;
            float bcol = bo[col];
#pragma unroll
            for (int r = 0; r < 4; ++r) {
                int row = m0 + wm + i * 16 + l4 * 4 + r;
                float resid = b2f(xt[(size_t)row * 512 + col]);
                out[(size_t)row * 512 + col] = acc[i][j][r] + bcol + resid;
            }
        }
}

extern "C" void kernel_launch(void* const* d_in, const int* in_sizes, int n_in,
                              void* d_out, int out_size, void* d_ws, size_t ws_size,
                              hipStream_t stream) {
    const float* x   = (const float*)d_in[0];
    const float* wq  = (const float*)d_in[1];
    const float* bq  = (const float*)d_in[2];
    const float* wk  = (const float*)d_in[3];
    const float* bk  = (const float*)d_in[4];
    const float* wv  = (const float*)d_in[5];
    const float* bv  = (const float*)d_in[6];
    const float* lng = (const float*)d_in[7];
    const float* lnb = (const float*)d_in[8];
    const float* wo  = (const float*)d_in[9];
    const float* bo  = (const float*)d_in[10];
    float* out = (float*)d_out;

    unsigned short* ws  = (unsigned short*)d_ws;
    const size_t M1 = (size_t)1024 * 1024;
    unsigned short* tn   = ws;               // 4M elems (8 MB); reused as ao after qkv
    unsigned short* qkvb = ws + 4 * M1;      // q @ +0, k @ +4M, vt @ +8M (24 MB)
    unsigned short* wT   = ws + 16 * M1;     // 1M elems (2 MB)
    unsigned short* xt   = ws + 17 * M1;     // 4M elems (8 MB)
    unsigned short* ao   = tn;

    wtrans_kernel<<<dim3(16, 16, 4), dim3(32, 8), 0, stream>>>(wq, wk, wv, wo, wT);
    xtrans_kernel<<<dim3(32, 16, 8), dim3(32, 8), 0, stream>>>(x, xt);
    ln_kernel<<<2048, 256, 0, stream>>>(xt, lng, lnb, tn);
    gemm_qkv_kernel<<<dim3(64, 4, 3), 256, 0, stream>>>(tn, wT, bq, bk, bv, qkvb);
    attn_kernel<<<dim3(16, 8, 8), 256, 0, stream>>>(qkvb,
                                                    qkvb + (size_t)MM * 512,
                                                    qkvb + (size_t)2 * MM * 512,
                                                    ao);
    gemm_out_kernel<<<dim3(64, 4), 256, 0, stream>>>(ao, wT + (size_t)3 * 512 * 512, bo, xt, out);
}

// Round 3
// 188.018 us; speedup vs baseline: 1.5672x; 1.0926x over previous
//
#include <hip/hip_runtime.h>
#include <hip/hip_bf16.h>
#include <stdint.h>

#define BB 8
#define CC 512
#define SS 1024
#define NH 8
#define DK 64
#define MM (BB*SS)      // 8192 rows
#define PQ 72           // P_lds pitch (elems): 144B rows, 16B-aligned

typedef __attribute__((ext_vector_type(8))) short bf16x8;
typedef __attribute__((ext_vector_type(4))) float f32x4;

__device__ inline float b2f(unsigned short u) {
    union { unsigned int i; float f; } x; x.i = ((unsigned int)u) << 16; return x.f;
}
__device__ inline unsigned short f2b(float f) {
    union { float f; unsigned int i; } x; x.f = f;
    unsigned int r = (x.i + 0x7FFFu + ((x.i >> 16) & 1u)) >> 16;
    return (unsigned short)r;
}
__device__ inline unsigned int cvtpk(float lo, float hi) {
    unsigned int r;
    asm("v_cvt_pk_bf16_f32 %0, %1, %2" : "=v"(r) : "v"(lo), "v"(hi));
    return r;
}
__device__ inline f32x4 mfma16(bf16x8 a, bf16x8 b, f32x4 c) {
    return __builtin_amdgcn_mfma_f32_16x16x32_bf16(a, b, c, 0, 0, 0);
}
__device__ __forceinline__ void gload16(const void* g, void* l) {
    __builtin_amdgcn_global_load_lds(
        (const __attribute__((address_space(1))) void*)g,
        (__attribute__((address_space(3))) void*)l, 16, 0, 0);
}

// ---------------- weight transpose + bf16 cast: w[K][N] -> wT[N][K] ----------------
__global__ void wtrans_kernel(const float* __restrict__ wq, const float* __restrict__ wk,
                              const float* __restrict__ wv, const float* __restrict__ wo,
                              unsigned short* __restrict__ wT) {
    __shared__ float lds[32][33];
    const float* w = (blockIdx.z == 0) ? wq : (blockIdx.z == 1) ? wk : (blockIdx.z == 2) ? wv : wo;
    unsigned short* o = wT + (size_t)blockIdx.z * (512 * 512);
    const int n0 = blockIdx.x * 32, k0 = blockIdx.y * 32;
    const int tx = threadIdx.x, ty = threadIdx.y;   // 32 x 8
#pragma unroll
    for (int i = 0; i < 4; ++i)
        lds[ty + 8 * i][tx] = w[(size_t)(k0 + ty + 8 * i) * 512 + n0 + tx];
    __syncthreads();
#pragma unroll
    for (int i = 0; i < 4; ++i)
        o[(size_t)(n0 + ty + 8 * i) * 512 + k0 + tx] = f2b(lds[tx][ty + 8 * i]);
}

// ---------------- x transpose: x fp32 [B][C][S] -> xt bf16 [B][S][C] ----------------
__global__ void xtrans_kernel(const float* __restrict__ x, unsigned short* __restrict__ xt) {
    __shared__ float lds[32][33];
    const int s0 = blockIdx.x * 32, c0 = blockIdx.y * 32, b = blockIdx.z;
    const int tx = threadIdx.x, ty = threadIdx.y;   // 32 x 8
#pragma unroll
    for (int i = 0; i < 4; ++i)
        lds[ty + 8 * i][tx] = x[((size_t)b * 512 + c0 + ty + 8 * i) * 1024 + s0 + tx];
    __syncthreads();
#pragma unroll
    for (int i = 0; i < 4; ++i)
        xt[((size_t)b * 1024 + s0 + ty + 8 * i) * 512 + c0 + tx] = f2b(lds[tx][ty + 8 * i]);
}

// ---------------- LayerNorm over C on xt rows -> tn bf16 [B*S][C] ----------------
__global__ void __launch_bounds__(256) ln_kernel(const unsigned short* __restrict__ xt,
                                                 const float* __restrict__ g,
                                                 const float* __restrict__ bta,
                                                 unsigned short* __restrict__ tn) {
    const int t = threadIdx.x, lane = t & 63, w = t >> 6;
    const int row = blockIdx.x * 4 + w;           // 0..8191
    bf16x8 v = *(const bf16x8*)(xt + (size_t)row * 512 + lane * 8);
    float f[8], sum = 0.f, sq = 0.f;
#pragma unroll
    for (int e = 0; e < 8; ++e) { f[e] = b2f((unsigned short)v[e]); sum += f[e]; sq += f[e] * f[e]; }
#pragma unroll
    for (int m = 1; m <= 32; m <<= 1) { sum += __shfl_xor(sum, m); sq += __shfl_xor(sq, m); }
    const float mean = sum * (1.f / 512.f);
    const float var = sq * (1.f / 512.f) - mean * mean;
    const float rstd = rsqrtf(var + 1e-5f);
    const float4 g0 = *(const float4*)(g + lane * 8), g1 = *(const float4*)(g + lane * 8 + 4);
    const float4 b0 = *(const float4*)(bta + lane * 8), b1 = *(const float4*)(bta + lane * 8 + 4);
    const float gg[8] = {g0.x, g0.y, g0.z, g0.w, g1.x, g1.y, g1.z, g1.w};
    const float bb[8] = {b0.x, b0.y, b0.z, b0.w, b1.x, b1.y, b1.z, b1.w};
    bf16x8 out;
#pragma unroll
    for (int e = 0; e < 8; ++e)
        out[e] = (short)f2b((f[e] - mean) * rstd * gg[e] + bb[e]);
    *(bf16x8*)(tn + (size_t)row * 512 + lane * 8) = out;
}

// ---------------- shared m97-style 128x128 GEMM core (global_load_lds, linear LDS) ----
// A [M][512] bf16 row-major, Bt [N][512] bf16 (B transposed, n-major)
__device__ inline void gemm_tile(const unsigned short* __restrict__ A,
                                 const unsigned short* __restrict__ Bt,
                                 int m0, int n0,
                                 unsigned short* A_lds, unsigned short* B_lds,
                                 f32x4 acc[4][4]) {
    const int t = threadIdx.x;
    const int lane = t & 63, w = t >> 6;
    const int l15 = lane & 15, l4 = lane >> 4;
    const int wm = (w >> 1) * 64, wn = (w & 1) * 64;
#pragma unroll 1
    for (int kt = 0; kt < 8; ++kt) {
        __syncthreads();   // all waves done reading previous tile
#pragma unroll
        for (int i = 0; i < 4; ++i) {
            int chunk = i * 256 + t;
            int row = chunk >> 3, kc = (chunk & 7) * 8;
            gload16(A + (size_t)(m0 + row) * 512 + kt * 64 + kc, &A_lds[chunk * 8]);
            gload16(Bt + (size_t)(n0 + row) * 512 + kt * 64 + kc, &B_lds[chunk * 8]);
        }
        __syncthreads();   // + implicit vmcnt(0): tile resident
#pragma unroll
        for (int kk = 0; kk < 2; ++kk) {
            bf16x8 af[4], bfr[4];
#pragma unroll
            for (int i = 0; i < 4; ++i)
                af[i] = *(const bf16x8*)&A_lds[(wm + i * 16 + l15) * 64 + kk * 32 + l4 * 8];
#pragma unroll
            for (int j = 0; j < 4; ++j)
                bfr[j] = *(const bf16x8*)&B_lds[(wn + j * 16 + l15) * 64 + kk * 32 + l4 * 8];
#pragma unroll
            for (int i = 0; i < 4; ++i)
#pragma unroll
                for (int j = 0; j < 4; ++j)
                    acc[i][j] = mfma16(af[i], bfr[j], acc[i][j]);
        }
    }
}

// ---------------- QKV projection GEMM; V written pre-transposed [b][h][d][s] --------
__global__ void __launch_bounds__(256) gemm_qkv_kernel(const unsigned short* __restrict__ tn,
                                                       const unsigned short* __restrict__ wT,
                                                       const float* __restrict__ bq,
                                                       const float* __restrict__ bk,
                                                       const float* __restrict__ bv,
                                                       unsigned short* __restrict__ outbase) {
    __shared__ alignas(16) unsigned short A_lds[128 * 64];
    __shared__ alignas(16) unsigned short B_lds[128 * 64];
    const int z = blockIdx.z;
    const unsigned short* Bt = wT + (size_t)z * (512 * 512);
    const float* bias = (z == 0) ? bq : (z == 1) ? bk : bv;
    const int m0 = blockIdx.x * 128, n0 = blockIdx.y * 128;
    f32x4 acc[4][4];
    const f32x4 z4 = {0.f, 0.f, 0.f, 0.f};
#pragma unroll
    for (int i = 0; i < 4; ++i)
#pragma unroll
        for (int j = 0; j < 4; ++j) acc[i][j] = z4;
    gemm_tile(tn, Bt, m0, n0, A_lds, B_lds, acc);
    const int lane = threadIdx.x & 63, w = threadIdx.x >> 6;
    const int l15 = lane & 15, l4 = lane >> 4;
    const int wm = (w >> 1) * 64, wn = (w & 1) * 64;
    if (z < 2) {
        unsigned short* out = outbase + (size_t)z * MM * 512;
#pragma unroll
        for (int i = 0; i < 4; ++i)
#pragma unroll
            for (int j = 0; j < 4; ++j) {
                int col = n0 + wn + j * 16 + l15;
                float bcol = bias[col];
#pragma unroll
                for (int r = 0; r < 4; ++r) {
                    int row = m0 + wm + i * 16 + l4 * 4 + r;
                    out[(size_t)row * 512 + col] = f2b(acc[i][j][r] + bcol);
                }
            }
    } else {
        // vt[(b*512 + col)*1024 + s], 4 consecutive s per lane -> 8B packed store
        unsigned short* vt = outbase + (size_t)2 * MM * 512;
#pragma unroll
        for (int i = 0; i < 4; ++i)
#pragma unroll
            for (int j = 0; j < 4; ++j) {
                int col = n0 + wn + j * 16 + l15;
                float bcol = bias[col];
                int rowb = m0 + wm + i * 16 + l4 * 4;
                int bi = rowb >> 10, s0 = rowb & 1023;
                unsigned int lo = (unsigned int)f2b(acc[i][j][0] + bcol) |
                                  ((unsigned int)f2b(acc[i][j][1] + bcol) << 16);
                unsigned int hi = (unsigned int)f2b(acc[i][j][2] + bcol) |
                                  ((unsigned int)f2b(acc[i][j][3] + bcol) << 16);
                uint2 pk; pk.x = lo; pk.y = hi;
                *(uint2*)&vt[((size_t)bi * 512 + col) * 1024 + s0] = pk;
            }
    }
}

// ---------------- flash attention v3: swapped QK^T, in-register softmax ----
// Per wave: 16 q rows (q = l15). QK^T computed transposed: sc[j][r] = S[key][q=l15].
// Row stats (m,l) are per-lane scalars; l kept as per-lane partial, reduced at end.
__global__ void __launch_bounds__(256) attn_kernel(const unsigned short* __restrict__ q,
                                                   const unsigned short* __restrict__ k,
                                                   const unsigned short* __restrict__ vt,
                                                   unsigned short* __restrict__ o) {
    __shared__ alignas(16) unsigned short Kl[2][64 * 64];   // [key][d], source-swizzled
    __shared__ alignas(16) unsigned short Vl[2][64 * 64];   // [d][key], source-swizzled
    __shared__ alignas(16) unsigned short Pl[4][16 * PQ];   // per-wave P [q][key]
    const int qt = blockIdx.x, h = blockIdx.y, b = blockIdx.z;
    const int t = threadIdx.x, lane = t & 63, w = t >> 6;
    const int l15 = lane & 15, l4 = lane >> 4;

    // Q B-fragments (col=q=l15, k=d contiguous), pre-scaled by 1/sqrt(64)
    const int qrow = qt * 64 + w * 16 + l15;
    const unsigned short* qp = q + ((size_t)(b * SS + qrow)) * 512 + h * 64;
    bf16x8 qf[2];
#pragma unroll
    for (int kk = 0; kk < 2; ++kk) {
        bf16x8 tmp = *(const bf16x8*)(qp + kk * 32 + l4 * 8);
#pragma unroll
        for (int e = 0; e < 8; ++e)
            tmp[e] = (short)f2b(b2f((unsigned short)tmp[e]) * 0.125f);
        qf[kk] = tmp;
    }

    const unsigned short* krow_base = k + ((size_t)(b * SS)) * 512 + h * 64;
    const unsigned short* vrow_base = vt + ((size_t)(b * NH + h) * DK) * SS;

    // staging: linear LDS dest, XOR-swizzled global source (involution on byte bits 4-6)
    auto STAGE = [&](int bi, int kt) {
        const int key0 = kt * 64;
#pragma unroll
        for (int i = 0; i < 2; ++i) {
            int chunk = i * 256 + t;
            int row = chunk >> 3;
            int scb = ((chunk & 7) * 16) ^ ((row & 7) << 4);
            gload16((const char*)(krow_base + (size_t)(key0 + row) * 512) + scb,
                    &Kl[bi][chunk * 8]);
            gload16((const char*)(vrow_base + (size_t)row * SS + key0) + scb,
                    &Vl[bi][chunk * 8]);
        }
    };

    float m_run = -1e30f, l_run = 0.f;   // per-lane: stats for q=l15 (l partial over l4 subset)
    f32x4 acc_o[4];                       // acc_o[j][r] = O[q=l4*4+r][d=j*16+l15]
    const f32x4 z4 = {0.f, 0.f, 0.f, 0.f};
#pragma unroll
    for (int j = 0; j < 4; ++j) acc_o[j] = z4;

    STAGE(0, 0);
    __syncthreads();

#pragma unroll 1
    for (int kt = 0; kt < 16; ++kt) {
        const int bi = kt & 1;
        if (kt < 15) STAGE(bi ^ 1, kt + 1);   // issue next tile early; drained at barrier

        // S^T = K @ Q^T : sc[j][r] = S[key=j*16+l4*4+r][q=l15]
        f32x4 sc[4];
#pragma unroll
        for (int j = 0; j < 4; ++j) sc[j] = z4;
#pragma unroll
        for (int kk = 0; kk < 2; ++kk)
#pragma unroll
            for (int j = 0; j < 4; ++j) {
                int row = j * 16 + l15;
                int cb = (kk * 64 + l4 * 16) ^ ((row & 7) << 4);
                bf16x8 kf = *(const bf16x8*)((const char*)Kl[bi] + row * 128 + cb);
                sc[j] = mfma16(kf, qf[kk], sc[j]);
            }

        // in-lane max over this lane's 16 keys, then reduce across l4 replicas
        float mx = fmaxf(fmaxf(sc[0][0], sc[0][1]), fmaxf(sc[0][2], sc[0][3]));
#pragma unroll
        for (int j = 1; j < 4; ++j)
            mx = fmaxf(mx, fmaxf(fmaxf(sc[j][0], sc[j][1]), fmaxf(sc[j][2], sc[j][3])));
        mx = fmaxf(mx, __shfl_xor(mx, 16));
        mx = fmaxf(mx, __shfl_xor(mx, 32));
        const float mnew = fmaxf(m_run, mx);
        const float scl = __expf(m_run - mnew);
        m_run = mnew;

        float p[4][4], lsum = 0.f;
#pragma unroll
        for (int j = 0; j < 4; ++j)
#pragma unroll
            for (int r = 0; r < 4; ++r) {
                p[j][r] = __expf(sc[j][r] - mnew);
                lsum += p[j][r];
            }
        l_run = l_run * scl + lsum;

        // write P[q=l15][key=j*16+l4*4 .. +3] as one b64 per j
#pragma unroll
        for (int j = 0; j < 4; ++j) {
            uint2 pk;
            pk.x = cvtpk(p[j][0], p[j][1]);
            pk.y = cvtpk(p[j][2], p[j][3]);
            *(uint2*)&Pl[w][l15 * PQ + j * 16 + l4 * 4] = pk;
        }

        // rescale O: row q=l4*4+r needs scl from lane q (lanes 0..15 hold q=0..15)
        float scl_r[4];
#pragma unroll
        for (int r = 0; r < 4; ++r) scl_r[r] = __shfl(scl, (l4 << 2) | r);
#pragma unroll
        for (int j = 0; j < 4; ++j)
#pragma unroll
            for (int r = 0; r < 4; ++r) acc_o[j][r] *= scl_r[r];

        // O += P @ V  (A = P[q][k] from wave-private LDS, B = V^T key-contiguous)
#pragma unroll
        for (int kk = 0; kk < 2; ++kk) {
            bf16x8 pf = *(const bf16x8*)&Pl[w][l15 * PQ + kk * 32 + l4 * 8];
#pragma unroll
            for (int j = 0; j < 4; ++j) {
                int row = j * 16 + l15;
                int cb = (kk * 64 + l4 * 16) ^ ((row & 7) << 4);
                bf16x8 vf = *(const bf16x8*)((const char*)Vl[bi] + row * 128 + cb);
                acc_o[j] = mfma16(pf, vf, acc_o[j]);
            }
        }

        __syncthreads();   // implicit vmcnt(0): next tile resident; reads of buf done
    }

    // total l per q: sum the 4 per-lane partials, then broadcast to output rows
    float l_tot = l_run;
    l_tot += __shfl_xor(l_tot, 16);
    l_tot += __shfl_xor(l_tot, 32);
    float l_r[4];
#pragma unroll
    for (int r = 0; r < 4; ++r) l_r[r] = __shfl(l_tot, (l4 << 2) | r);

#pragma unroll
    for (int j = 0; j < 4; ++j)
#pragma unroll
        for (int r = 0; r < 4; ++r) {
            int row = qt * 64 + w * 16 + l4 * 4 + r;
            float val = acc_o[j][r] / l_r[r];
            o[((size_t)(b * SS + row)) * 512 + h * 64 + j * 16 + l15] = f2b(val);
        }
}

// ---------------- output projection + bias + residual (coalesced bf16 resid) --------
__global__ void __launch_bounds__(256) gemm_out_kernel(const unsigned short* __restrict__ ao,
                                                       const unsigned short* __restrict__ woT,
                                                       const float* __restrict__ bo,
                                                       const unsigned short* __restrict__ xt,
                                                       float* __restrict__ out) {
    __shared__ alignas(16) unsigned short A_lds[128 * 64];
    __shared__ alignas(16) unsigned short B_lds[128 * 64];
    const int m0 = blockIdx.x * 128, n0 = blockIdx.y * 128;
    f32x4 acc[4][4];
    const f32x4 z4 = {0.f, 0.f, 0.f, 0.f};
#pragma unroll
    for (int i = 0; i < 4; ++i)
#pragma unroll
        for (int j = 0; j < 4; ++j) acc[i][j] = z4;
    gemm_tile(ao, woT, m0, n0, A_lds, B_lds, acc);
    const int lane = threadIdx.x & 63, w = threadIdx.x >> 6;
    const int l15 = lane & 15, l4 = lane >> 4;
    const int wm = (w >> 1) * 64, wn = (w & 1) * 64;
#pragma unroll
    for (int i = 0; i < 4; ++i)
#pragma unroll
        for (int j = 0; j < 4; ++j) {
            int col = n0 + wn + j * 16 + l15;
            float bcol = bo[col];
#pragma unroll
            for (int r = 0; r < 4; ++r) {
                int row = m0 + wm + i * 16 + l4 * 4 + r;
                float resid = b2f(xt[(size_t)row * 512 + col]);
                out[(size_t)row * 512 + col] = acc[i][j][r] + bcol + resid;
            }
        }
}

extern "C" void kernel_launch(void* const* d_in, const int* in_sizes, int n_in,
                              void* d_out, int out_size, void* d_ws, size_t ws_size,
                              hipStream_t stream) {
    const float* x   = (const float*)d_in[0];
    const float* wq  = (const float*)d_in[1];
    const float* bq  = (const float*)d_in[2];
    const float* wk  = (const float*)d_in[3];
    const float* bk  = (const float*)d_in[4];
    const float* wv  = (const float*)d_in[5];
    const float* bv  = (const float*)d_in[6];
    const float* lng = (const float*)d_in[7];
    const float* lnb = (const float*)d_in[8];
    const float* wo  = (const float*)d_in[9];
    const float* bo  = (const float*)d_in[10];
    float* out = (float*)d_out;

    unsigned short* ws  = (unsigned short*)d_ws;
    const size_t M1 = (size_t)1024 * 1024;
    unsigned short* tn   = ws;               // 4M elems (8 MB); reused as ao after qkv
    unsigned short* qkvb = ws + 4 * M1;      // q @ +0, k @ +4M, vt @ +8M (24 MB)
    unsigned short* wT   = ws + 16 * M1;     // 1M elems (2 MB)
    unsigned short* xt   = ws + 17 * M1;     // 4M elems (8 MB)
    unsigned short* ao   = tn;

    wtrans_kernel<<<dim3(16, 16, 4), dim3(32, 8), 0, stream>>>(wq, wk, wv, wo, wT);
    xtrans_kernel<<<dim3(32, 16, 8), dim3(32, 8), 0, stream>>>(x, xt);
    ln_kernel<<<2048, 256, 0, stream>>>(xt, lng, lnb, tn);
    gemm_qkv_kernel<<<dim3(64, 4, 3), 256, 0, stream>>>(tn, wT, bq, bk, bv, qkvb);
    attn_kernel<<<dim3(16, 8, 8), 256, 0, stream>>>(qkvb,
                                                    qkvb + (size_t)MM * 512,
                                                    qkvb + (size_t)2 * MM * 512,
                                                    ao);
    gemm_out_kernel<<<dim3(64, 4), 256, 0, stream>>>(ao, wT + (size_t)3 * 512 * 512, bo, xt, out);
}